// Round 5
// baseline (404.762 us; speedup 1.0000x reference)
//
#include <hip/hip_runtime.h>

#define P_PTS 131072
#define CDIM  512
#define MCAP  1024
#define TLEN  262144
#define PORIG 163840

typedef unsigned short u16;
typedef unsigned char  u8;
typedef __attribute__((ext_vector_type(8))) short short8;
typedef __attribute__((ext_vector_type(4))) float f32x4;
typedef __attribute__((ext_vector_type(8))) int int8v;
typedef __attribute__((ext_vector_type(4))) int int4v;

__device__ __forceinline__ u16 f2bf(float f) {
    unsigned u = __float_as_uint(f);
    unsigned r = (u + 0x7FFFu + ((u >> 16) & 1u)) >> 16;
    return (u16)r;
}
// OCP e4m3 decode: normals AND subnormals via f32-subnormal trick
__device__ __forceinline__ float d_e4m3(unsigned x) {
    float f = __uint_as_float((x & 0x7Fu) << 20) * 0x1p120f;
    return __uint_as_float(__float_as_uint(f) | ((x & 0x80u) << 24));
}
__device__ __forceinline__ void ld16(const void* g, void* l) {
    __builtin_amdgcn_global_load_lds(
        (const __attribute__((address_space(1))) void*)g,
        (__attribute__((address_space(3))) void*)l, 16, 0, 0);
}

// ---- fused prep. Block ranges:
//  [0,32768)        gather+normalize -> feats8
//  [32768,33280)    cap cast bf16 + ptom scatter
//  [33280,33792)    lse_sum zero
//  [33792,33920)    B pre-swizzle -> Bswz
//  [33920,34944)    segment boundary scan -> starts[1025]
__global__ __launch_bounds__(256) void gather_prep(
    const float* __restrict__ adapter, const int* __restrict__ v2p,
    const float* __restrict__ cap, const int* __restrict__ oidx,
    const int* __restrict__ seg,
    u8* __restrict__ feats8, u16* __restrict__ capb, u8* __restrict__ Bswz,
    int* __restrict__ ptom, float* __restrict__ lse_sum,
    int* __restrict__ starts) {
    int b = blockIdx.x, tid = threadIdx.x;
    if (b < 32768) {
        int p = b * 4 + (tid >> 6);
        int lane = tid & 63;
        int vrow = v2p[p];
        const float4* src = (const float4*)(adapter + (size_t)vrow * CDIM);
        float4 x0 = src[lane * 2];
        float4 x1 = src[lane * 2 + 1];
        float ss = x0.x*x0.x + x0.y*x0.y + x0.z*x0.z + x0.w*x0.w
                 + x1.x*x1.x + x1.y*x1.y + x1.z*x1.z + x1.w*x1.w;
        #pragma unroll
        for (int off = 32; off >= 1; off >>= 1) ss += __shfl_xor(ss, off, 64);
        float inv = 1.0f / fmaxf(sqrtf(ss), 1e-12f);
        int lo = __builtin_amdgcn_cvt_pk_fp8_f32(x0.x*inv, x0.y*inv, 0, false);
        lo = __builtin_amdgcn_cvt_pk_fp8_f32(x0.z*inv, x0.w*inv, lo, true);
        int hi = __builtin_amdgcn_cvt_pk_fp8_f32(x1.x*inv, x1.y*inv, 0, false);
        hi = __builtin_amdgcn_cvt_pk_fp8_f32(x1.z*inv, x1.w*inv, hi, true);
        uint2 w; w.x = (unsigned)lo; w.y = (unsigned)hi;
        *(uint2*)(feats8 + (size_t)p * CDIM + lane * 8) = w;
    } else if (b < 33280) {
        int t = (b - 32768) * 256 + tid;       // [0, 131072)
        int i = t * 4;
        float4 v = *(const float4*)(cap + i);
        u16* o = capb + i;
        o[0] = f2bf(v.x); o[1] = f2bf(v.y); o[2] = f2bf(v.z); o[3] = f2bf(v.w);
        atomicMax(&ptom[oidx[t]], t);          // last-write-wins == max (t increasing)
    } else if (b < 33792) {
        int j = (b - 33280) * 256 + tid;       // [0, 131072)
        lse_sum[j] = 0.0f;
    } else if (b < 33920) {
        // B pre-swizzle into MFMA fragment order (16B granule g2)
        int g2 = (b - 33792) * 256 + tid;      // [0, 32768)
        int c    = g2 & 1;
        int lane = (g2 >> 1) & 63;
        int j    = (g2 >> 7) & 3;
        int kk   = (g2 >> 9) & 3;
        int wn   = (g2 >> 11) & 1;
        int c0   = g2 >> 12;
        int col  = c0 * 128 + wn * 64 + j * 16 + (lane & 15);
        int kb   = kk * 128 + (lane >> 4) * 32 + c * 16;
        const float* s = cap + (size_t)col * CDIM + kb;
        unsigned w4[4];
        #pragma unroll
        for (int u = 0; u < 4; ++u) {
            int p = __builtin_amdgcn_cvt_pk_fp8_f32(s[u*4+0], s[u*4+1], 0, false);
            p = __builtin_amdgcn_cvt_pk_fp8_f32(s[u*4+2], s[u*4+3], p, true);
            w4[u] = (unsigned)p;
        }
        *(uint4*)(Bswz + (size_t)g2 * 16) = *(uint4*)w4;
    } else {
        // starts[s] = first t with seg[t] >= s (seg sorted ascending)
        int t = (b - 33920) * 256 + tid;       // [0, TLEN)
        int hi = seg[t];
        int lo = (t == 0) ? -1 : seg[t - 1];
        for (int s = lo + 1; s <= hi; ++s) starts[s] = t;
        if (t == TLEN - 1)
            for (int s = hi + 1; s <= MCAP; ++s) starts[s] = TLEN;
    }
}

// ---- heavy GEMM: MX-fp8 K=128 MFMA, 128x128 tiles; A via double-buffered LDS
//      (prefetch next phase before compute -> only prologue vmcnt drain exposed);
//      B direct-from-global pre-swizzled, software-pipelined one phase ahead;
//      tail blocks (>=8192) do make_rows. Epilogue exp-reduce -> atomicAdd ----
__global__ __launch_bounds__(256) void lse_gemm(
    const u8* __restrict__ feats8, const u8* __restrict__ Bswz,
    const float* __restrict__ lsc, float* __restrict__ lse_sum,
    const int* __restrict__ ctpm, const int* __restrict__ ptom,
    unsigned* __restrict__ rows) {
    if (blockIdx.x >= 8192) {                  // make_rows tail
        int t = (blockIdx.x - 8192) * 256 + threadIdx.x;
        int g = ptom[ctpm[t]];
        rows[t] = (g < 0) ? ((unsigned)(g + P_PTS) | 0x80000000u) : (unsigned)g;
        return;
    }
    __shared__ __align__(16) u8 As[2][16384];
    const int tid  = threadIdx.x;
    const int wave = tid >> 6;
    const int lane = tid & 63;
    const unsigned id = blockIdx.x;
    const int c0   = (int)((id >> 3) & 7u);
    const int row0 = (int)((id & 7u) + 8u * (id >> 6)) * 128;
    const int wm = (wave >> 1) * 64;
    const int wn1 = (wave & 1);
    const float sf = __expf(lsc[0]);

    f32x4 acc[4][4] = {};

    const int srow = tid >> 3;                 // 0..31
    const int kc   = (tid & 7) ^ (srow & 7);
    const u8* gA = feats8 + (size_t)(row0 + srow) * CDIM + kc * 16;

    const int m = lane & 15;
    const int q = lane >> 4;
    const int a1off = ((wm + m) * 8 + ((2*q)   ^ (m & 7))) * 16;
    const int a2off = ((wm + m) * 8 + ((2*q+1) ^ (m & 7))) * 16;
    const u8* bw = Bswz + (size_t)(c0 * 2 + wn1) * 16 * 2048 + lane * 32;

    int8v bv[2][4];
    // prologue: stage phase 0 A, load phase 0 B
    #pragma unroll
    for (int c = 0; c < 4; ++c)
        ld16(gA + (size_t)c * 32 * CDIM, As[0] + wave * 1024 + c * 4096);
    #pragma unroll
    for (int j = 0; j < 4; ++j) {
        const u8* p = bw + j * 2048;
        int4v lo = *(const int4v*)p;
        int4v hi = *(const int4v*)(p + 16);
        bv[0][j][0]=lo[0]; bv[0][j][1]=lo[1]; bv[0][j][2]=lo[2]; bv[0][j][3]=lo[3];
        bv[0][j][4]=hi[0]; bv[0][j][5]=hi[1]; bv[0][j][6]=hi[2]; bv[0][j][7]=hi[3];
    }

    #pragma unroll
    for (int kk = 0; kk < 4; ++kk) {
        __syncthreads();   // drains phase-kk ld16 (in flight one compute-phase for kk>0)
        if (kk < 3) {
            // issue next-phase A staging + next-phase B regs; consumed NEXT iter
            #pragma unroll
            for (int c = 0; c < 4; ++c)
                ld16(gA + (size_t)c * 32 * CDIM + (kk + 1) * 128,
                     As[(kk + 1) & 1] + wave * 1024 + c * 4096);
            #pragma unroll
            for (int j = 0; j < 4; ++j) {
                const u8* p = bw + ((kk + 1) * 4 + j) * 2048;
                int4v lo = *(const int4v*)p;
                int4v hi = *(const int4v*)(p + 16);
                int kb = (kk + 1) & 1;
                bv[kb][j][0]=lo[0]; bv[kb][j][1]=lo[1]; bv[kb][j][2]=lo[2]; bv[kb][j][3]=lo[3];
                bv[kb][j][4]=hi[0]; bv[kb][j][5]=hi[1]; bv[kb][j][6]=hi[2]; bv[kb][j][7]=hi[3];
            }
        }
        const u8* base = As[kk & 1];
        int8v af[4];
        #pragma unroll
        for (int i = 0; i < 4; ++i) {
            int4v lo = *(const int4v*)(base + a1off + i * 2048);
            int4v hi = *(const int4v*)(base + a2off + i * 2048);
            af[i][0]=lo[0]; af[i][1]=lo[1]; af[i][2]=lo[2]; af[i][3]=lo[3];
            af[i][4]=hi[0]; af[i][5]=hi[1]; af[i][6]=hi[2]; af[i][7]=hi[3];
        }
        #pragma unroll
        for (int i = 0; i < 4; ++i)
            #pragma unroll
            for (int j = 0; j < 4; ++j)
                acc[i][j] = __builtin_amdgcn_mfma_scale_f32_16x16x128_f8f6f4(
                    af[i], bv[kk & 1][j], acc[i][j], 0, 0, 0, 127, 0, 127);
    }

    #pragma unroll
    for (int i = 0; i < 4; ++i) {
        float s4[4] = {0.f, 0.f, 0.f, 0.f};
        #pragma unroll
        for (int j = 0; j < 4; ++j)
            #pragma unroll
            for (int r = 0; r < 4; ++r)
                s4[r] += __expf(acc[i][j][r] * sf - sf);
        #pragma unroll
        for (int off = 8; off >= 1; off >>= 1)
            #pragma unroll
            for (int r = 0; r < 4; ++r)
                s4[r] += __shfl_xor(s4[r], off, 64);
        if (m == 0) {
            int rbase = row0 + wm + i * 16 + q * 4;
            #pragma unroll
            for (int r = 0; r < 4; ++r)
                atomicAdd(&lse_sum[rbase + r], s4[r]);
        }
    }
}

#define ACC8(v)                                              \
    a[0] += d_e4m3((v).x);       a[1] += d_e4m3((v).x >> 8); \
    a[2] += d_e4m3((v).x >> 16); a[3] += d_e4m3((v).x >> 24);\
    a[4] += d_e4m3((v).y);       a[5] += d_e4m3((v).y >> 8); \
    a[6] += d_e4m3((v).y >> 16); a[7] += d_e4m3((v).y >> 24);

// ---- per-segment: Fb[s] = sum feats rows (bf16), L[s] = sum log lse_sum, counts ----
__global__ __launch_bounds__(1024) void seg_reduce(
    const u8* __restrict__ feats8, const float* __restrict__ lse_sum,
    const unsigned* __restrict__ rows, const int* __restrict__ starts,
    const float* __restrict__ lsc,
    u16* __restrict__ Fb, float* __restrict__ Lout, float* __restrict__ realn) {
    int s = blockIdx.x;
    int tid = threadIdx.x, wave = tid >> 6, lane = tid & 63;
    int start = starts[s];
    int end   = starts[s + 1];
    float a[8] = {0,0,0,0,0,0,0,0};
    float Lacc = 0.f; int inv = 0;
    int r = start + wave;
    for (; r + 48 < end; r += 64) {          // 4-way MLP
        unsigned p0 = rows[r], p1 = rows[r+16], p2 = rows[r+32], p3 = rows[r+48];
        int r0 = (int)(p0 & 0x7FFFFFFFu), r1 = (int)(p1 & 0x7FFFFFFFu);
        int r2 = (int)(p2 & 0x7FFFFFFFu), r3 = (int)(p3 & 0x7FFFFFFFu);
        uint2 v0 = *(const uint2*)(feats8 + (size_t)r0 * CDIM + lane * 8);
        uint2 v1 = *(const uint2*)(feats8 + (size_t)r1 * CDIM + lane * 8);
        uint2 v2 = *(const uint2*)(feats8 + (size_t)r2 * CDIM + lane * 8);
        uint2 v3 = *(const uint2*)(feats8 + (size_t)r3 * CDIM + lane * 8);
        if (lane == 0) {
            inv += (int)(p0>>31) + (int)(p1>>31) + (int)(p2>>31) + (int)(p3>>31);
            Lacc += __logf(lse_sum[r0]) + __logf(lse_sum[r1])
                  + __logf(lse_sum[r2]) + __logf(lse_sum[r3]);
        }
        ACC8(v0) ACC8(v1) ACC8(v2) ACC8(v3)
    }
    for (; r < end; r += 16) {
        unsigned p0 = rows[r];
        int r0 = (int)(p0 & 0x7FFFFFFFu);
        uint2 v0 = *(const uint2*)(feats8 + (size_t)r0 * CDIM + lane * 8);
        if (lane == 0) { inv += (int)(p0 >> 31); Lacc += __logf(lse_sum[r0]); }
        ACC8(v0)
    }
    __shared__ float pF[16][512];
    __shared__ float pL[16];
    __shared__ int   pI[16];
    #pragma unroll
    for (int u = 0; u < 8; ++u) pF[wave][lane * 8 + u] = a[u];
    if (lane == 0) { pL[wave] = Lacc; pI[wave] = inv; }
    __syncthreads();
    if (tid < 512) {
        float f = 0.f;
        #pragma unroll
        for (int w = 0; w < 16; ++w) f += pF[w][tid];
        Fb[(size_t)s * CDIM + tid] = f2bf(f);
    }
    if (tid == 0) {
        float cnt = (float)(end - start);
        float Ls = 0.f; int ninv = 0;
        #pragma unroll
        for (int w = 0; w < 16; ++w) { Ls += pL[w]; ninv += pI[w]; }
        realn[s] = cnt - (float)ninv;
        Lout[s] = Ls + __expf(lsc[0]) * cnt;   // each lse = sf + log(sum)
    }
}

// ---- pooled[s,m] = (sf*Fb[s].capb[m] - L[s]) * (1/real or 0); 64x64 bf16 MFMA ----
__global__ __launch_bounds__(256) void pooled_gemm(
    const u16* __restrict__ Fb, const u16* __restrict__ capb,
    const float* __restrict__ Lout, const float* __restrict__ realn,
    const float* __restrict__ lsc, float* __restrict__ out) {
    __shared__ __align__(16) u16 As[64 * 32];
    __shared__ __align__(16) u16 Bs[64 * 32];
    const int tid  = threadIdx.x;
    const int wave = tid >> 6;
    const int lane = tid & 63;
    const int col0 = blockIdx.x * 64;   // captions
    const int row0 = blockIdx.y * 64;   // segments
    const int wm = (wave >> 1) * 32;
    const int wn = (wave & 1) * 32;
    const float sf = __expf(lsc[0]);
    f32x4 acc[2][2] = {};
    const int srow = tid >> 2;          // 0..63
    const int scol = (tid & 3) * 8;
    const u16* gA0 = Fb   + (size_t)(row0 + srow) * CDIM + scol;
    const u16* gB0 = capb + (size_t)(col0 + srow) * CDIM + scol;
    u16* lA0 = As + wave * 512;
    u16* lB0 = Bs + wave * 512;
    const int mrow = lane & 15;
    const int quad = lane >> 4;
    const u16* rA = As + (wm + mrow) * 32 + quad * 8;
    const u16* rB = Bs + (wn + mrow) * 32 + quad * 8;
    #pragma unroll 4
    for (int k0 = 0; k0 < CDIM; k0 += 32) {
        __syncthreads();
        ld16(gA0 + k0, lA0);
        ld16(gB0 + k0, lB0);
        __syncthreads();
        short8 af[2], bfr[2];
        #pragma unroll
        for (int i = 0; i < 2; ++i) af[i]  = *(const short8*)(rA + i * 512);
        #pragma unroll
        for (int j = 0; j < 2; ++j) bfr[j] = *(const short8*)(rB + j * 512);
        #pragma unroll
        for (int i = 0; i < 2; ++i)
            #pragma unroll
            for (int j = 0; j < 2; ++j)
                acc[i][j] = __builtin_amdgcn_mfma_f32_16x16x32_bf16(
                    af[i], bfr[j], acc[i][j], 0, 0, 0);
    }
    #pragma unroll
    for (int i = 0; i < 2; ++i) {
        #pragma unroll
        for (int r = 0; r < 4; ++r) {
            int s = row0 + wm + i * 16 + quad * 4 + r;
            float rn = realn[s];
            float dn = rn > 0.f ? 1.0f / rn : 0.0f;
            float L = Lout[s];
            #pragma unroll
            for (int j = 0; j < 2; ++j) {
                int mc = col0 + wn + j * 16 + mrow;
                out[(size_t)s * MCAP + mc] = (sf * acc[i][j][r] - L) * dn;
            }
        }
    }
    if (col0 == 0 && tid < 64) {
        int s = row0 + tid;
        float rv = realn[s];
        out[MCAP * MCAP + s] = rv;
        out[MCAP * MCAP + MCAP + s] = (rv > 0.f) ? 1.0f : 0.0f;
    }
}

extern "C" void kernel_launch(void* const* d_in, const int* in_sizes, int n_in,
                              void* d_out, int out_size, void* d_ws, size_t ws_size,
                              hipStream_t stream) {
    const float* adapter = (const float*)d_in[0];
    const float* cap     = (const float*)d_in[1];
    const float* lsc     = (const float*)d_in[2];
    const int*   v2p     = (const int*)d_in[3];
    const int*   oidx    = (const int*)d_in[4];
    const int*   ctpm    = (const int*)d_in[5];
    const int*   seg     = (const int*)d_in[6];
    float* out = (float*)d_out;

    char* ws = (char*)d_ws;
    u8*       feats8  = (u8*)(ws);                                // 67,108,864 B
    u16*      capb    = (u16*)(ws + 67108864);                    //  1,048,576 B
    u8*       Bswz    = (u8*)(ws + 68157440);                     //    524,288 B
    float*    lse_sum = (float*)(ws + 68681728);                  //    524,288 B
    int*      ptom    = (int*)(ws + 69206016);                    //    655,360 B
    unsigned* rows    = (unsigned*)(ws + 69861376);               //  1,048,576 B
    u16*      Fb      = (u16*)(ws + 70909952);                    //  1,048,576 B
    float*    Lout    = (float*)(ws + 71958528);                  //      4,096 B
    float*    realn   = (float*)(ws + 71962624);                  //      4,096 B
    int*      starts  = (int*)(ws + 71966720);                    //      4,112 B

    hipMemsetAsync(ptom, 0xFF, (size_t)PORIG * 4, stream);        // -1

    gather_prep<<<34944, 256, 0, stream>>>(adapter, v2p, cap, oidx, seg,
                                           feats8, capb, Bswz, ptom, lse_sum, starts);
    lse_gemm<<<8192 + TLEN / 256, 256, 0, stream>>>(feats8, Bswz, lsc, lse_sum,
                                                    ctpm, ptom, rows);
    seg_reduce<<<MCAP, 1024, 0, stream>>>(feats8, lse_sum, rows, starts, lsc, Fb, Lout, realn);
    pooled_gemm<<<dim3(MCAP / 64, MCAP / 64), 256, 0, stream>>>(Fb, capb, Lout, realn, lsc, out);
}